// Round 8
// baseline (1981.414 us; speedup 1.0000x reference)
//
#include <hip/hip_runtime.h>
#include <hip/hip_bf16.h>

// Problem constants
#define B_ 256
#define T_ 96
#define F_ 368
#define H_ 368
#define G3_ 1104          // 3*H
#define NC_ 29            // fine classes
#define BT_ (B_*T_)       // 24576
#define HB_ (H_*B_)       // 94208, one time-slice of temporal [u][b]

// GRU geometry
#define NSL 8             // unit slices
#define NU 46             // units per slice (8*46 = 368)
#define NCOL 138          // cols per slice = 3*NU
#define SLSTRIDE 144      // padded col positions per slice (64+64+16)
#define WQCOLS 1152       // 8 * 144
#define ROWS 8            // batch rows per group

#define F4C(v, i) ((i)==0?(v).x:((i)==1?(v).y:((i)==2?(v).z:(v).w)))

// ---- fence-free cross-XCD exchange primitives (proven in round 5) --------
// RELAXED agent-scope atomics = global_load/store sc0 sc1: bypass L1/L2,
// complete at the cross-XCD coherence point, NO cache maintenance.
__device__ __forceinline__ void bstore_f(float* p, float v) {
    __hip_atomic_store(p, v, __ATOMIC_RELAXED, __HIP_MEMORY_SCOPE_AGENT);
}
__device__ __forceinline__ int bload_i(const int* p) {
    return __hip_atomic_load(p, __ATOMIC_RELAXED, __HIP_MEMORY_SCOPE_AGENT);
}
__device__ __forceinline__ float2 bload_f2(const float* p) {
    unsigned long long v = __hip_atomic_load(
        reinterpret_cast<const unsigned long long*>(p),
        __ATOMIC_RELAXED, __HIP_MEMORY_SCOPE_AGENT);
    float2 f2; __builtin_memcpy(&f2, &v, 8);
    return f2;
}

// ---------------------------------------------------------------------------
// K0: pack Wh (1104x368) into Wq float4 blocks [kb=92][1152 colpos]
// ---------------------------------------------------------------------------
__global__ __launch_bounds__(256) void k_prep_wq(const float* __restrict__ Wh,
                                                 float4* __restrict__ Wq) {
    const int idx = blockIdx.x*256 + threadIdx.x;   // < 92*1152 = 105984
    const int kb = idx / WQCOLS, cp = idx - kb*WQCOLS;
    const int us = cp / SLSTRIDE, r = cp - us*SLSTRIDE;
    float4 v = make_float4(0.f,0.f,0.f,0.f);
    if (r < NCOL) {
        const int g = r / NU, u = r - g*NU;
        const int grow = g*H_ + us*NU + u;          // < 1104
        v = *reinterpret_cast<const float4*>(Wh + (size_t)grow*H_ + 4*kb);
    }
    Wq[idx] = v;
}

// ---------------------------------------------------------------------------
// K0b: pack head weights Wcat[u][32]
// ---------------------------------------------------------------------------
__global__ __launch_bounds__(256) void k_prep_wcat(const float* __restrict__ Wc,
                                                   const float* __restrict__ Wf,
                                                   float* __restrict__ Wcat) {
    const int idx = blockIdx.x*256 + threadIdx.x;   // < 368*32 = 11776
    const int u = idx >> 5, c = idx & 31;
    float v = 0.f;
    if (c < 2) v = Wc[c*H_ + u];
    else if (c < 31) v = Wf[(c-2)*H_ + u];
    Wcat[idx] = v;
}

// ---------------------------------------------------------------------------
// K0c: zero flag words at the coherence point
// ---------------------------------------------------------------------------
__global__ __launch_bounds__(256) void k_zero_bar(int* __restrict__ bar) {
    __hip_atomic_store(bar + blockIdx.x*256 + threadIdx.x, 0,
                       __ATOMIC_RELAXED, __HIP_MEMORY_SCOPE_AGENT);
}

// ---------------------------------------------------------------------------
// K1: xproj GEMM, 128x128 tile, pipelined; 4 WGs/CU via launch bounds.
// ---------------------------------------------------------------------------
__global__ __launch_bounds__(256, 4) void k_xproj_gemm(const float* __restrict__ A,
                                                       const float* __restrict__ Bw,
                                                       const float* __restrict__ bias,
                                                       float* __restrict__ C) {
    __shared__ float As[16][128];
    __shared__ float Bs[16][128];
    const int tid = threadIdx.x;
    const int tx = tid & 15, ty = tid >> 4;
    const int gm0 = blockIdx.y * 128, gn0 = blockIdx.x * 128;
    const float4* A4 = reinterpret_cast<const float4*>(A);   // row stride 92
    const float4* B4 = reinterpret_cast<const float4*>(Bw);
    const int lm = tid & 127;
    const int kh = (tid >> 7) * 2;
    const int gn = gn0 + lm;

    float acc[8][8];
    #pragma unroll
    for (int i = 0; i < 8; ++i)
        #pragma unroll
        for (int j = 0; j < 8; ++j) acc[i][j] = 0.f;

    float4 va[2], vb[2];
    #pragma unroll
    for (int q = 0; q < 2; ++q) {
        va[q] = A4[(size_t)(gm0 + lm)*92 + kh + q];
        vb[q] = (gn < G3_) ? B4[(size_t)gn*92 + kh + q] : make_float4(0.f,0.f,0.f,0.f);
    }

    for (int kt = 0; kt < 23; ++kt) {
        __syncthreads();
        #pragma unroll
        for (int q = 0; q < 2; ++q) {
            As[(kh+q)*4+0][lm] = va[q].x; As[(kh+q)*4+1][lm] = va[q].y;
            As[(kh+q)*4+2][lm] = va[q].z; As[(kh+q)*4+3][lm] = va[q].w;
            Bs[(kh+q)*4+0][lm] = vb[q].x; Bs[(kh+q)*4+1][lm] = vb[q].y;
            Bs[(kh+q)*4+2][lm] = vb[q].z; Bs[(kh+q)*4+3][lm] = vb[q].w;
        }
        __syncthreads();
        const int ktn = (kt < 22) ? kt + 1 : 22;
        #pragma unroll
        for (int q = 0; q < 2; ++q) {
            va[q] = A4[(size_t)(gm0 + lm)*92 + ktn*4 + kh + q];
            vb[q] = (gn < G3_) ? B4[(size_t)gn*92 + ktn*4 + kh + q]
                               : make_float4(0.f,0.f,0.f,0.f);
        }
        #pragma unroll
        for (int k = 0; k < 16; ++k) {
            const float4 a0 = *reinterpret_cast<const float4*>(&As[k][ty*4]);
            const float4 a1 = *reinterpret_cast<const float4*>(&As[k][64 + ty*4]);
            const float4 b0 = *reinterpret_cast<const float4*>(&Bs[k][tx*4]);
            const float4 b1 = *reinterpret_cast<const float4*>(&Bs[k][64 + tx*4]);
            #pragma unroll
            for (int i = 0; i < 4; ++i) {
                const float ai0 = F4C(a0, i), ai1 = F4C(a1, i);
                #pragma unroll
                for (int j = 0; j < 4; ++j) {
                    const float bj0 = F4C(b0, j), bj1 = F4C(b1, j);
                    acc[i][j]     = fmaf(ai0, bj0, acc[i][j]);
                    acc[i][j+4]   = fmaf(ai0, bj1, acc[i][j+4]);
                    acc[i+4][j]   = fmaf(ai1, bj0, acc[i+4][j]);
                    acc[i+4][j+4] = fmaf(ai1, bj1, acc[i+4][j+4]);
                }
            }
        }
    }
    #pragma unroll
    for (int i = 0; i < 8; ++i) {
        const int gm = gm0 + ((i < 4) ? (ty*4 + i) : (64 + ty*4 + i - 4));
        #pragma unroll
        for (int j = 0; j < 8; ++j) {
            const int gnn = gn0 + ((j < 4) ? (tx*4 + j) : (64 + tx*4 + j - 4));
            if (gnn < G3_) C[(size_t)gm*G3_ + gnn] = acc[i][j] + bias[gnn];
        }
    }
}

// ---------------------------------------------------------------------------
// K2 v7: PERSISTENT GRU, 512 threads (8 waves = 2/SIMD). EXACT round-5 sync
// structure (tid0 spin on single counter -> syncthreads -> cooperative stage
// -> syncthreads -> FMA; partials -> syncthreads -> gates -> syncthreads ->
// fetch_add publish). Only the within-WG compute partitioning changed:
// 8 waves split K eight ways (kb windows 12,11,12,11,... of 92), so W
// streams stay disjoint (no L2 inflation) and 2 waves/SIMD hide each
// other's W-load / ds_read stalls. All LDS h traffic float2-typed.
// ---------------------------------------------------------------------------
__global__ __launch_bounds__(512, 2) void k_gru_all(const float* __restrict__ xproj,
                                                    const float4* __restrict__ Wq,
                                                    const float* __restrict__ bh,
                                                    float* __restrict__ temporal,
                                                    int* __restrict__ bar) {
    __shared__ float part[8][ROWS][SLSTRIDE];   // 36,864 B
    __shared__ float2 hsl2[1472];               // h(t-1)[u][rowpair], 11,776 B
    const int tid = threadIdx.x;
    const int us  = blockIdx.x & 7;             // this WG's slice
    const int bg  = blockIdx.x >> 3;            // 0..31
    const int b0  = bg * ROWS;
    const int w   = tid >> 6;                   // wave 0..7
    const int l   = tid & 63;
    const int l3  = 128 + (l & 15);
    const int off = (23*w + (w & 1)) >> 1;      // kb window start: 0,12,23,35,46,58,69,81
    const int cnt = 12 - (w & 1);               // kb count: 12,11,12,11,...
    int* mybar = bar + bg*64;                   // single counter per bg (round-5)

    // gate-phase constants (one item per thread, tid < 368)
    const bool gact = tid < ROWS*NU;
    const int u1 = tid % NU, r1 = tid / NU;
    const int ug1 = us*NU + u1;
    float bh1r = 0.f, bh1z = 0.f, bh1n = 0.f;
    if (gact) { bh1r = bh[ug1]; bh1z = bh[H_+ug1]; bh1n = bh[2*H_+ug1]; }

    const float4* wp = Wq + (size_t)off*WQCOLS + us*SLSTRIDE;

    for (int t = 0; t < T_; ++t) {
        float* hout = temporal + (size_t)t*HB_;

        // prefetch gate operands (independent of h; hides under spin)
        float xg10 = 0.f, xg11 = 0.f, xg12 = 0.f;
        if (gact) {
            const float* xr1 = xproj + ((size_t)(b0 + r1)*T_ + t)*G3_;
            xg10 = xr1[ug1]; xg11 = xr1[H_+ug1]; xg12 = xr1[2*H_+ug1];
        }

        float acc[ROWS][3];
        #pragma unroll
        for (int r = 0; r < ROWS; ++r) { acc[r][0]=0.f; acc[r][1]=0.f; acc[r][2]=0.f; }

        if (t > 0) {
            // round-5 proven: tid0 spins until all 8 bg-siblings published h(t-1)
            if (tid == 0) {
                while (bload_i(mybar) < 8*t) {}
            }
            __syncthreads();
            const float* hin = temporal + (size_t)(t - 1)*HB_;
            // cooperative stage h(t-1)[368 units][8 rows] as 1472 float2 slots
            #pragma unroll
            for (int ii = 0; ii < 3; ++ii) {
                const int s = tid + ii*512;
                if (s < 1472) {
                    const int u = s >> 2, pr = s & 3;
                    hsl2[s] = bload_f2(hin + (size_t)u*B_ + b0 + 2*pr);
                }
            }
            __syncthreads();
            // inner product over this wave's kb window, W pipelined from L2
            float4 w0 = wp[l], w1 = wp[64 + l], w2 = wp[l3];
            for (int kk = 0; kk < cnt; ++kk) {
                const int kkn = (kk + 1 < cnt) ? kk + 1 : kk;
                const float4* np = wp + (size_t)kkn*WQCOLS;
                const float4 nw0 = np[l], nw1 = np[64 + l], nw2 = np[l3];
                const int ub = 4*(off + kk);
                #pragma unroll
                for (int jk = 0; jk < 4; ++jk) {
                    const int u = ub + jk;
                    const float2 h01 = hsl2[u*4 + 0];
                    const float2 h23 = hsl2[u*4 + 1];
                    const float2 h45 = hsl2[u*4 + 2];
                    const float2 h67 = hsl2[u*4 + 3];
                    const float wa = F4C(w0, jk), wb = F4C(w1, jk), wc = F4C(w2, jk);
                    acc[0][0] = fmaf(h01.x, wa, acc[0][0]);
                    acc[0][1] = fmaf(h01.x, wb, acc[0][1]);
                    acc[0][2] = fmaf(h01.x, wc, acc[0][2]);
                    acc[1][0] = fmaf(h01.y, wa, acc[1][0]);
                    acc[1][1] = fmaf(h01.y, wb, acc[1][1]);
                    acc[1][2] = fmaf(h01.y, wc, acc[1][2]);
                    acc[2][0] = fmaf(h23.x, wa, acc[2][0]);
                    acc[2][1] = fmaf(h23.x, wb, acc[2][1]);
                    acc[2][2] = fmaf(h23.x, wc, acc[2][2]);
                    acc[3][0] = fmaf(h23.y, wa, acc[3][0]);
                    acc[3][1] = fmaf(h23.y, wb, acc[3][1]);
                    acc[3][2] = fmaf(h23.y, wc, acc[3][2]);
                    acc[4][0] = fmaf(h45.x, wa, acc[4][0]);
                    acc[4][1] = fmaf(h45.x, wb, acc[4][1]);
                    acc[4][2] = fmaf(h45.x, wc, acc[4][2]);
                    acc[5][0] = fmaf(h45.y, wa, acc[5][0]);
                    acc[5][1] = fmaf(h45.y, wb, acc[5][1]);
                    acc[5][2] = fmaf(h45.y, wc, acc[5][2]);
                    acc[6][0] = fmaf(h67.x, wa, acc[6][0]);
                    acc[6][1] = fmaf(h67.x, wb, acc[6][1]);
                    acc[6][2] = fmaf(h67.x, wc, acc[6][2]);
                    acc[7][0] = fmaf(h67.y, wa, acc[7][0]);
                    acc[7][1] = fmaf(h67.y, wb, acc[7][1]);
                    acc[7][2] = fmaf(h67.y, wc, acc[7][2]);
                }
                w0 = nw0; w1 = nw1; w2 = nw2;
            }
        }

        // k-window partials (block3: lane-cousins write identical values)
        #pragma unroll
        for (int r = 0; r < ROWS; ++r) {
            part[w][r][l]      = acc[r][0];
            part[w][r][64 + l] = acc[r][1];
            part[w][r][l3]     = acc[r][2];
        }
        __syncthreads();

        // fused gates: one (unit,row) per thread
        if (gact) {
            float s0 = 0.f, s1 = 0.f, s2 = 0.f;
            #pragma unroll
            for (int q = 0; q < 8; ++q) {
                s0 += part[q][r1][u1];
                s1 += part[q][r1][NU + u1];
                s2 += part[q][r1][2*NU + u1];
            }
            const float rg = 1.f/(1.f + expf(-(xg10 + s0 + bh1r)));
            const float zg = 1.f/(1.f + expf(-(xg11 + s1 + bh1z)));
            const float ng = tanhf(xg12 + rg*(s2 + bh1n));
            float hp = 0.f;
            if (t > 0) {
                const float2 hv = hsl2[ug1*4 + (r1 >> 1)];
                hp = (r1 & 1) ? hv.y : hv.x;
            }
            bstore_f(hout + (size_t)ug1*B_ + b0 + r1, (1.f - zg)*ng + zg*hp);
        }
        // every wave drains vmcnt before s_barrier => all h(t) bypass stores
        // are at the coherence point before the publish below (round-5 proven)
        __syncthreads();
        if (tid == 0) {
            __hip_atomic_fetch_add(mybar, 1, __ATOMIC_RELAXED,
                                   __HIP_MEMORY_SCOPE_AGENT);
        }
    }
}

// ---------------------------------------------------------------------------
// K3: heads on temporal [t][u][b] (kernel boundary = full visibility)
// ---------------------------------------------------------------------------
__global__ __launch_bounds__(256) void k_heads2(const float* __restrict__ temporal,
                                                const float* __restrict__ Wcat,
                                                const float* __restrict__ bc,
                                                const float* __restrict__ bf,
                                                float* __restrict__ cs,
                                                float* __restrict__ fine_out) {
    const int t = blockIdx.x;       // 0..95
    const int b = threadIdx.x;      // 0..255
    const float* tb = temporal + (size_t)t*HB_ + b;
    float acc[31];
    #pragma unroll
    for (int c = 0; c < 31; ++c) acc[c] = 0.f;
    for (int u = 0; u < H_; ++u) {
        const float x = tb[(size_t)u*B_];
        const float* wrow = Wcat + u*32;
        #pragma unroll
        for (int c = 0; c < 31; ++c) acc[c] = fmaf(x, wrow[c], acc[c]);
    }
    const float l0 = acc[0] + bc[0], l1 = acc[1] + bc[1];
    const float m  = fmaxf(l0, l1);
    const float e0 = expf(l0 - m), e1 = expf(l1 - m);
    const float inv = 1.f/(e0 + e1);
    cs[((size_t)b*T_ + t)*2]     = e0*inv;
    cs[((size_t)b*T_ + t)*2 + 1] = e1*inv;
    #pragma unroll
    for (int c = 2; c < 31; ++c) {
        fine_out[((size_t)b*T_ + t)*NC_ + (c-2)] = 1.f/(1.f + expf(-(acc[c] + bf[c-2])));
    }
}

// ---------------------------------------------------------------------------
// K4: NMS + argmax
// ---------------------------------------------------------------------------
__global__ __launch_bounds__(256) void k_nms(const float* __restrict__ cs,
                                             float* __restrict__ out_dec,
                                             float* __restrict__ out_nms) {
    const int idx = blockIdx.x*256 + threadIdx.x;   // < 24576
    const int t = idx % T_;
    const float bg = cs[idx*2], s1 = cs[idx*2+1];
    float wmin = bg;
    #pragma unroll
    for (int dt = -2; dt <= 2; ++dt) {
        const int tt = t + dt;
        if (dt != 0 && tt >= 0 && tt < T_) wmin = fminf(wmin, cs[(idx + dt)*2]);
    }
    const bool keep = (bg <= wmin);
    out_dec[idx]     = (keep && (s1 > bg)) ? 1.f : 0.f;
    out_nms[idx*2]   = keep ? bg : 0.f;
    out_nms[idx*2+1] = keep ? s1 : 0.f;
}

// ---------------------------------------------------------------------------
extern "C" void kernel_launch(void* const* d_in, const int* in_sizes, int n_in,
                              void* d_out, int out_size, void* d_ws, size_t ws_size,
                              hipStream_t stream) {
    const float* features = (const float*)d_in[0];
    const float* Wi = (const float*)d_in[2];
    const float* Wh = (const float*)d_in[3];
    const float* bi = (const float*)d_in[4];
    const float* bh = (const float*)d_in[5];
    const float* Wc = (const float*)d_in[6];
    const float* bc = (const float*)d_in[7];
    const float* Wf = (const float*)d_in[8];
    const float* bf = (const float*)d_in[9];

    float* out = (float*)d_out;
    float* out_dec  = out;                 // (B,T)     24576
    float* out_nms  = out + BT_;           // (B,T,2)   49152
    float* out_fine = out + BT_ + 2*BT_;   // (B,T,29)  712704

    // workspace (floats): xproj | Wq | temporal | bar (2048 ints)
    float* xproj    = (float*)d_ws;
    float4* Wq      = (float4*)(xproj + (size_t)BT_*G3_);
    float* temporal = xproj + (size_t)BT_*G3_ + (size_t)92*WQCOLS*4;
    int*   bar      = (int*)(temporal + (size_t)T_*HB_);
    float* Wcat     = xproj;               // xproj dead after GRU
    float* cs       = xproj + 12288;

    k_zero_bar<<<8, 256, 0, stream>>>(bar);
    k_prep_wq<<<414, 256, 0, stream>>>(Wh, Wq);
    k_xproj_gemm<<<dim3(9, 192), 256, 0, stream>>>(features, Wi, bi, xproj);
    k_gru_all<<<256, 512, 0, stream>>>(xproj, Wq, bh, temporal, bar);
    k_prep_wcat<<<46, 256, 0, stream>>>(Wc, Wf, Wcat);
    k_heads2<<<96, 256, 0, stream>>>(temporal, Wcat, bc, bf, cs, out_fine);
    k_nms<<<96, 256, 0, stream>>>(cs, out_dec, out_nms);
}

// Round 9
// 1149.716 us; speedup vs baseline: 1.7234x; 1.7234x over previous
//
#include <hip/hip_runtime.h>
#include <hip/hip_bf16.h>

// Problem constants
#define B_ 256
#define T_ 96
#define F_ 368
#define H_ 368
#define G3_ 1104          // 3*H
#define NC_ 29            // fine classes
#define BT_ (B_*T_)       // 24576
#define HB_ (H_*B_)       // 94208, one time-slice of temporal [u][b]

// GRU geometry
#define NSL 8             // unit slices
#define NU 46             // units per slice (8*46 = 368)
#define NCOL 138          // cols per slice = 3*NU
#define SLSTRIDE 144      // padded col positions per slice (64+64+16)
#define WQCOLS 1152       // 8 * 144
#define ROWS 8            // batch rows per group

#define F4C(v, i) ((i)==0?(v).x:((i)==1?(v).y:((i)==2?(v).z:(v).w)))

// ---- fence-free cross-XCD exchange primitives (proven in rounds 5/8) ------
// RELAXED agent-scope atomics = global_load/store sc0 sc1: bypass L1/L2,
// complete at the cross-XCD coherence point, NO cache maintenance.
__device__ __forceinline__ void bstore_f(float* p, float v) {
    __hip_atomic_store(p, v, __ATOMIC_RELAXED, __HIP_MEMORY_SCOPE_AGENT);
}
__device__ __forceinline__ int bload_i(const int* p) {
    return __hip_atomic_load(p, __ATOMIC_RELAXED, __HIP_MEMORY_SCOPE_AGENT);
}
__device__ __forceinline__ float2 bload_f2(const float* p) {
    unsigned long long v = __hip_atomic_load(
        reinterpret_cast<const unsigned long long*>(p),
        __ATOMIC_RELAXED, __HIP_MEMORY_SCOPE_AGENT);
    float2 f2; __builtin_memcpy(&f2, &v, 8);
    return f2;
}

// ---------------------------------------------------------------------------
// K0: pack Wh (1104x368) into Wq float4 blocks [kb=92][1152 colpos]
// ---------------------------------------------------------------------------
__global__ __launch_bounds__(256) void k_prep_wq(const float* __restrict__ Wh,
                                                 float4* __restrict__ Wq) {
    const int idx = blockIdx.x*256 + threadIdx.x;   // < 92*1152 = 105984
    const int kb = idx / WQCOLS, cp = idx - kb*WQCOLS;
    const int us = cp / SLSTRIDE, r = cp - us*SLSTRIDE;
    float4 v = make_float4(0.f,0.f,0.f,0.f);
    if (r < NCOL) {
        const int g = r / NU, u = r - g*NU;
        const int grow = g*H_ + us*NU + u;          // < 1104
        v = *reinterpret_cast<const float4*>(Wh + (size_t)grow*H_ + 4*kb);
    }
    Wq[idx] = v;
}

// ---------------------------------------------------------------------------
// K0b: pack head weights Wcat[u][32]
// ---------------------------------------------------------------------------
__global__ __launch_bounds__(256) void k_prep_wcat(const float* __restrict__ Wc,
                                                   const float* __restrict__ Wf,
                                                   float* __restrict__ Wcat) {
    const int idx = blockIdx.x*256 + threadIdx.x;   // < 368*32 = 11776
    const int u = idx >> 5, c = idx & 31;
    float v = 0.f;
    if (c < 2) v = Wc[c*H_ + u];
    else if (c < 31) v = Wf[(c-2)*H_ + u];
    Wcat[idx] = v;
}

// ---------------------------------------------------------------------------
// K0c: zero flag words at the coherence point
// ---------------------------------------------------------------------------
__global__ __launch_bounds__(256) void k_zero_bar(int* __restrict__ bar) {
    __hip_atomic_store(bar + blockIdx.x*256 + threadIdx.x, 0,
                       __ATOMIC_RELAXED, __HIP_MEMORY_SCOPE_AGENT);
}

// ---------------------------------------------------------------------------
// K1: xproj GEMM, 128x128 tile, pipelined. PLAIN launch bounds: round-8's
// (256,4) squeezed VGPR to 64 -> scratch spill (1.9 GB fetch + 2.7 GB write,
// dur 352->1104 us). Let the allocator pick (~92 VGPR, no spill).
// ---------------------------------------------------------------------------
__global__ __launch_bounds__(256) void k_xproj_gemm(const float* __restrict__ A,
                                                    const float* __restrict__ Bw,
                                                    const float* __restrict__ bias,
                                                    float* __restrict__ C) {
    __shared__ float As[16][128];
    __shared__ float Bs[16][128];
    const int tid = threadIdx.x;
    const int tx = tid & 15, ty = tid >> 4;
    const int gm0 = blockIdx.y * 128, gn0 = blockIdx.x * 128;
    const float4* A4 = reinterpret_cast<const float4*>(A);   // row stride 92
    const float4* B4 = reinterpret_cast<const float4*>(Bw);
    const int lm = tid & 127;
    const int kh = (tid >> 7) * 2;
    const int gn = gn0 + lm;

    float acc[8][8];
    #pragma unroll
    for (int i = 0; i < 8; ++i)
        #pragma unroll
        for (int j = 0; j < 8; ++j) acc[i][j] = 0.f;

    float4 va[2], vb[2];
    #pragma unroll
    for (int q = 0; q < 2; ++q) {
        va[q] = A4[(size_t)(gm0 + lm)*92 + kh + q];
        vb[q] = (gn < G3_) ? B4[(size_t)gn*92 + kh + q] : make_float4(0.f,0.f,0.f,0.f);
    }

    for (int kt = 0; kt < 23; ++kt) {
        __syncthreads();
        #pragma unroll
        for (int q = 0; q < 2; ++q) {
            As[(kh+q)*4+0][lm] = va[q].x; As[(kh+q)*4+1][lm] = va[q].y;
            As[(kh+q)*4+2][lm] = va[q].z; As[(kh+q)*4+3][lm] = va[q].w;
            Bs[(kh+q)*4+0][lm] = vb[q].x; Bs[(kh+q)*4+1][lm] = vb[q].y;
            Bs[(kh+q)*4+2][lm] = vb[q].z; Bs[(kh+q)*4+3][lm] = vb[q].w;
        }
        __syncthreads();
        const int ktn = (kt < 22) ? kt + 1 : 22;
        #pragma unroll
        for (int q = 0; q < 2; ++q) {
            va[q] = A4[(size_t)(gm0 + lm)*92 + ktn*4 + kh + q];
            vb[q] = (gn < G3_) ? B4[(size_t)gn*92 + ktn*4 + kh + q]
                               : make_float4(0.f,0.f,0.f,0.f);
        }
        #pragma unroll
        for (int k = 0; k < 16; ++k) {
            const float4 a0 = *reinterpret_cast<const float4*>(&As[k][ty*4]);
            const float4 a1 = *reinterpret_cast<const float4*>(&As[k][64 + ty*4]);
            const float4 b0 = *reinterpret_cast<const float4*>(&Bs[k][tx*4]);
            const float4 b1 = *reinterpret_cast<const float4*>(&Bs[k][64 + tx*4]);
            #pragma unroll
            for (int i = 0; i < 4; ++i) {
                const float ai0 = F4C(a0, i), ai1 = F4C(a1, i);
                #pragma unroll
                for (int j = 0; j < 4; ++j) {
                    const float bj0 = F4C(b0, j), bj1 = F4C(b1, j);
                    acc[i][j]     = fmaf(ai0, bj0, acc[i][j]);
                    acc[i][j+4]   = fmaf(ai0, bj1, acc[i][j+4]);
                    acc[i+4][j]   = fmaf(ai1, bj0, acc[i+4][j]);
                    acc[i+4][j+4] = fmaf(ai1, bj1, acc[i+4][j+4]);
                }
            }
        }
    }
    #pragma unroll
    for (int i = 0; i < 8; ++i) {
        const int gm = gm0 + ((i < 4) ? (ty*4 + i) : (64 + ty*4 + i - 4));
        #pragma unroll
        for (int j = 0; j < 8; ++j) {
            const int gnn = gn0 + ((j < 4) ? (tx*4 + j) : (64 + tx*4 + j - 4));
            if (gnn < G3_) C[(size_t)gm*G3_ + gnn] = acc[i][j] + bias[gnn];
        }
    }
}

// ---------------------------------------------------------------------------
// K2 v8: PERSISTENT GRU (round-8 passing structure, unchanged sync model:
// tid0 spin on single counter -> sync -> cooperative stage -> sync -> FMA ->
// partials -> sync -> gates -> sync -> fetch_add publish). Only change vs
// round 8: the kk=0 W prefetch (static Wq data, zero correctness surface)
// is issued BEFORE the spin so its L2 latency hides under the wait.
// ---------------------------------------------------------------------------
__global__ __launch_bounds__(512, 2) void k_gru_all(const float* __restrict__ xproj,
                                                    const float4* __restrict__ Wq,
                                                    const float* __restrict__ bh,
                                                    float* __restrict__ temporal,
                                                    int* __restrict__ bar) {
    __shared__ float part[8][ROWS][SLSTRIDE];   // 36,864 B
    __shared__ float2 hsl2[1472];               // h(t-1)[u][rowpair], 11,776 B
    const int tid = threadIdx.x;
    const int us  = blockIdx.x & 7;             // this WG's slice
    const int bg  = blockIdx.x >> 3;            // 0..31
    const int b0  = bg * ROWS;
    const int w   = tid >> 6;                   // wave 0..7
    const int l   = tid & 63;
    const int l3  = 128 + (l & 15);
    const int off = (23*w + (w & 1)) >> 1;      // kb window start: 0,12,23,35,46,58,69,81
    const int cnt = 12 - (w & 1);               // kb count: 12,11,12,11,...
    int* mybar = bar + bg*64;                   // single counter per bg

    // gate-phase constants (one item per thread, tid < 368)
    const bool gact = tid < ROWS*NU;
    const int u1 = tid % NU, r1 = tid / NU;
    const int ug1 = us*NU + u1;
    float bh1r = 0.f, bh1z = 0.f, bh1n = 0.f;
    if (gact) { bh1r = bh[ug1]; bh1z = bh[H_+ug1]; bh1n = bh[2*H_+ug1]; }

    const float4* wp = Wq + (size_t)off*WQCOLS + us*SLSTRIDE;

    for (int t = 0; t < T_; ++t) {
        float* hout = temporal + (size_t)t*HB_;

        // prefetch gate operands (independent of h; hides under spin)
        float xg10 = 0.f, xg11 = 0.f, xg12 = 0.f;
        if (gact) {
            const float* xr1 = xproj + ((size_t)(b0 + r1)*T_ + t)*G3_;
            xg10 = xr1[ug1]; xg11 = xr1[H_+ug1]; xg12 = xr1[2*H_+ug1];
        }

        float acc[ROWS][3];
        #pragma unroll
        for (int r = 0; r < ROWS; ++r) { acc[r][0]=0.f; acc[r][1]=0.f; acc[r][2]=0.f; }

        if (t > 0) {
            // kk=0 W prefetch BEFORE the spin: static data, L2 latency hides
            // under the flag wait + barriers.
            float4 w0 = wp[l], w1 = wp[64 + l], w2 = wp[l3];
            // proven sync: tid0 spins until all 8 bg-siblings published h(t-1)
            if (tid == 0) {
                while (bload_i(mybar) < 8*t) {}
            }
            __syncthreads();
            const float* hin = temporal + (size_t)(t - 1)*HB_;
            // cooperative stage h(t-1)[368 units][8 rows] as 1472 float2 slots
            #pragma unroll
            for (int ii = 0; ii < 3; ++ii) {
                const int s = tid + ii*512;
                if (s < 1472) {
                    const int u = s >> 2, pr = s & 3;
                    hsl2[s] = bload_f2(hin + (size_t)u*B_ + b0 + 2*pr);
                }
            }
            __syncthreads();
            // inner product over this wave's kb window, W pipelined from L2
            for (int kk = 0; kk < cnt; ++kk) {
                const int kkn = (kk + 1 < cnt) ? kk + 1 : kk;
                const float4* np = wp + (size_t)kkn*WQCOLS;
                const float4 nw0 = np[l], nw1 = np[64 + l], nw2 = np[l3];
                const int ub = 4*(off + kk);
                #pragma unroll
                for (int jk = 0; jk < 4; ++jk) {
                    const int u = ub + jk;
                    const float2 h01 = hsl2[u*4 + 0];
                    const float2 h23 = hsl2[u*4 + 1];
                    const float2 h45 = hsl2[u*4 + 2];
                    const float2 h67 = hsl2[u*4 + 3];
                    const float wa = F4C(w0, jk), wb = F4C(w1, jk), wc = F4C(w2, jk);
                    acc[0][0] = fmaf(h01.x, wa, acc[0][0]);
                    acc[0][1] = fmaf(h01.x, wb, acc[0][1]);
                    acc[0][2] = fmaf(h01.x, wc, acc[0][2]);
                    acc[1][0] = fmaf(h01.y, wa, acc[1][0]);
                    acc[1][1] = fmaf(h01.y, wb, acc[1][1]);
                    acc[1][2] = fmaf(h01.y, wc, acc[1][2]);
                    acc[2][0] = fmaf(h23.x, wa, acc[2][0]);
                    acc[2][1] = fmaf(h23.x, wb, acc[2][1]);
                    acc[2][2] = fmaf(h23.x, wc, acc[2][2]);
                    acc[3][0] = fmaf(h23.y, wa, acc[3][0]);
                    acc[3][1] = fmaf(h23.y, wb, acc[3][1]);
                    acc[3][2] = fmaf(h23.y, wc, acc[3][2]);
                    acc[4][0] = fmaf(h45.x, wa, acc[4][0]);
                    acc[4][1] = fmaf(h45.x, wb, acc[4][1]);
                    acc[4][2] = fmaf(h45.x, wc, acc[4][2]);
                    acc[5][0] = fmaf(h45.y, wa, acc[5][0]);
                    acc[5][1] = fmaf(h45.y, wb, acc[5][1]);
                    acc[5][2] = fmaf(h45.y, wc, acc[5][2]);
                    acc[6][0] = fmaf(h67.x, wa, acc[6][0]);
                    acc[6][1] = fmaf(h67.x, wb, acc[6][1]);
                    acc[6][2] = fmaf(h67.x, wc, acc[6][2]);
                    acc[7][0] = fmaf(h67.y, wa, acc[7][0]);
                    acc[7][1] = fmaf(h67.y, wb, acc[7][1]);
                    acc[7][2] = fmaf(h67.y, wc, acc[7][2]);
                }
                w0 = nw0; w1 = nw1; w2 = nw2;
            }
        }

        // k-window partials (block3: lane-cousins write identical values)
        #pragma unroll
        for (int r = 0; r < ROWS; ++r) {
            part[w][r][l]      = acc[r][0];
            part[w][r][64 + l] = acc[r][1];
            part[w][r][l3]     = acc[r][2];
        }
        __syncthreads();

        // fused gates: one (unit,row) per thread
        if (gact) {
            float s0 = 0.f, s1 = 0.f, s2 = 0.f;
            #pragma unroll
            for (int q = 0; q < 8; ++q) {
                s0 += part[q][r1][u1];
                s1 += part[q][r1][NU + u1];
                s2 += part[q][r1][2*NU + u1];
            }
            const float rg = 1.f/(1.f + expf(-(xg10 + s0 + bh1r)));
            const float zg = 1.f/(1.f + expf(-(xg11 + s1 + bh1z)));
            const float ng = tanhf(xg12 + rg*(s2 + bh1n));
            float hp = 0.f;
            if (t > 0) {
                const float2 hv = hsl2[ug1*4 + (r1 >> 1)];
                hp = (r1 & 1) ? hv.y : hv.x;
            }
            bstore_f(hout + (size_t)ug1*B_ + b0 + r1, (1.f - zg)*ng + zg*hp);
        }
        // every wave drains vmcnt before s_barrier => all h(t) bypass stores
        // are at the coherence point before the publish below
        __syncthreads();
        if (tid == 0) {
            __hip_atomic_fetch_add(mybar, 1, __ATOMIC_RELAXED,
                                   __HIP_MEMORY_SCOPE_AGENT);
        }
    }
}

// ---------------------------------------------------------------------------
// K3: heads on temporal [t][u][b] (kernel boundary = full visibility)
// ---------------------------------------------------------------------------
__global__ __launch_bounds__(256) void k_heads2(const float* __restrict__ temporal,
                                                const float* __restrict__ Wcat,
                                                const float* __restrict__ bc,
                                                const float* __restrict__ bf,
                                                float* __restrict__ cs,
                                                float* __restrict__ fine_out) {
    const int t = blockIdx.x;       // 0..95
    const int b = threadIdx.x;      // 0..255
    const float* tb = temporal + (size_t)t*HB_ + b;
    float acc[31];
    #pragma unroll
    for (int c = 0; c < 31; ++c) acc[c] = 0.f;
    for (int u = 0; u < H_; ++u) {
        const float x = tb[(size_t)u*B_];
        const float* wrow = Wcat + u*32;
        #pragma unroll
        for (int c = 0; c < 31; ++c) acc[c] = fmaf(x, wrow[c], acc[c]);
    }
    const float l0 = acc[0] + bc[0], l1 = acc[1] + bc[1];
    const float m  = fmaxf(l0, l1);
    const float e0 = expf(l0 - m), e1 = expf(l1 - m);
    const float inv = 1.f/(e0 + e1);
    cs[((size_t)b*T_ + t)*2]     = e0*inv;
    cs[((size_t)b*T_ + t)*2 + 1] = e1*inv;
    #pragma unroll
    for (int c = 2; c < 31; ++c) {
        fine_out[((size_t)b*T_ + t)*NC_ + (c-2)] = 1.f/(1.f + expf(-(acc[c] + bf[c-2])));
    }
}

// ---------------------------------------------------------------------------
// K4: NMS + argmax
// ---------------------------------------------------------------------------
__global__ __launch_bounds__(256) void k_nms(const float* __restrict__ cs,
                                             float* __restrict__ out_dec,
                                             float* __restrict__ out_nms) {
    const int idx = blockIdx.x*256 + threadIdx.x;   // < 24576
    const int t = idx % T_;
    const float bg = cs[idx*2], s1 = cs[idx*2+1];
    float wmin = bg;
    #pragma unroll
    for (int dt = -2; dt <= 2; ++dt) {
        const int tt = t + dt;
        if (dt != 0 && tt >= 0 && tt < T_) wmin = fminf(wmin, cs[(idx + dt)*2]);
    }
    const bool keep = (bg <= wmin);
    out_dec[idx]     = (keep && (s1 > bg)) ? 1.f : 0.f;
    out_nms[idx*2]   = keep ? bg : 0.f;
    out_nms[idx*2+1] = keep ? s1 : 0.f;
}

// ---------------------------------------------------------------------------
extern "C" void kernel_launch(void* const* d_in, const int* in_sizes, int n_in,
                              void* d_out, int out_size, void* d_ws, size_t ws_size,
                              hipStream_t stream) {
    const float* features = (const float*)d_in[0];
    const float* Wi = (const float*)d_in[2];
    const float* Wh = (const float*)d_in[3];
    const float* bi = (const float*)d_in[4];
    const float* bh = (const float*)d_in[5];
    const float* Wc = (const float*)d_in[6];
    const float* bc = (const float*)d_in[7];
    const float* Wf = (const float*)d_in[8];
    const float* bf = (const float*)d_in[9];

    float* out = (float*)d_out;
    float* out_dec  = out;                 // (B,T)     24576
    float* out_nms  = out + BT_;           // (B,T,2)   49152
    float* out_fine = out + BT_ + 2*BT_;   // (B,T,29)  712704

    // workspace (floats): xproj | Wq | temporal | bar (2048 ints)
    float* xproj    = (float*)d_ws;
    float4* Wq      = (float4*)(xproj + (size_t)BT_*G3_);
    float* temporal = xproj + (size_t)BT_*G3_ + (size_t)92*WQCOLS*4;
    int*   bar      = (int*)(temporal + (size_t)T_*HB_);
    float* Wcat     = xproj;               // xproj dead after GRU
    float* cs       = xproj + 12288;

    k_zero_bar<<<8, 256, 0, stream>>>(bar);
    k_prep_wq<<<414, 256, 0, stream>>>(Wh, Wq);
    k_xproj_gemm<<<dim3(9, 192), 256, 0, stream>>>(features, Wi, bi, xproj);
    k_gru_all<<<256, 512, 0, stream>>>(xproj, Wq, bh, temporal, bar);
    k_prep_wcat<<<46, 256, 0, stream>>>(Wc, Wf, Wcat);
    k_heads2<<<96, 256, 0, stream>>>(temporal, Wcat, bc, bf, cs, out_fine);
    k_nms<<<96, 256, 0, stream>>>(cs, out_dec, out_nms);
}